// Round 2
// 136.432 us; speedup vs baseline: 1.0244x; 1.0244x over previous
//
#include <hip/hip_runtime.h>

// DinoPool: block-diagonal uniform attention == per-512-row-block column mean,
// broadcast to all 512 rows. x, out: [4,4096,384] float32. x1/x2/mask unused.
//
// Scoreboard: R3 two-kernel=143.8us | R5 fused=153.0 (L2 amplification) |
// R4 coop=179.1 | R6 vec4 kernel A=139.8 (best) | R7 compile-fail
// (__builtin_nontemporal_* rejects HIP_vector_type float4 -> use
// ext_vector_type(4) native vector instead).
// R8 = R6 + kernel-B store-loop hoist (i%CH4 is loop-invariant since NT%CH4==0;
// keep mean float4 in a register, loop is pure stores) + nontemporal hints on
// the streaming paths (x read-once in A, out write-once in B). ws stays cached.
// Floor arithmetic: 25.2MB read + 25.2MB write + 0.8MB ws round-trip
// @6.6TB/s ≈ 8.5us + 2 graph dispatches. Harness re-poison (256MiB ws fill
// = 40.7us @82% peak + input restores) dominates dur_us; not controllable.

#define BB   4
#define SS   4096
#define CC   384          // H*D = 6*64
#define BLK  512
#define NBLK 8            // SS/BLK
#define NT   384          // threads per WG (6 waves)
#define RCH  8            // ws partials per block (kernel A WGs per block)
#define ROWS (BLK / RCH)  // 64 rows per kernel-A WG
#define NSUB 16           // kernel-B WGs per block
#define RWS  (BLK / NSUB) // 32 rows per kernel-B WG
#define CH4  (CC / 4)     // 96 float4 chunks per row

typedef float f32x4 __attribute__((ext_vector_type(4)));  // native vector:
// __builtin_nontemporal_* accepts this (HIP float4 is a struct and is rejected)

// ---------------------------------------------------------------------------
// Kernel A: 64-row partial column sums, nontemporal float4 loads.
// grid = BB*NBLK*RCH = 256, block = 384 (4 row-groups x 96 float4-chunks).
// ---------------------------------------------------------------------------
__global__ __launch_bounds__(NT) void colsum_f32(
    const float* __restrict__ x, float* __restrict__ ws) {
  __shared__ float part[4][CC];             // 6 KB

  int bid = blockIdx.x;                     // (b*NBLK + blk)*RCH + r
  int r   = bid & (RCH - 1);
  int blk = (bid >> 3) & (NBLK - 1);
  int b   = bid >> 6;
  int t   = threadIdx.x;
  int cq  = t % CH4;                        // float4 chunk within a row
  int g   = t / CH4;                        // row group 0..3

  const f32x4* xv =
      (const f32x4*)(x + (size_t)(b * SS + blk * BLK + r * ROWS) * CC);
  float a0 = 0.f, a1 = 0.f, a2 = 0.f, a3 = 0.f;
#pragma unroll
  for (int k = 0; k < ROWS / 4; ++k) {      // 16 iters: rows g, g+4, ...
    f32x4 v = __builtin_nontemporal_load(&xv[(size_t)(g + 4 * k) * CH4 + cq]);
    a0 += v.x; a1 += v.y; a2 += v.z; a3 += v.w;
  }
  part[g][cq * 4 + 0] = a0;
  part[g][cq * 4 + 1] = a1;
  part[g][cq * 4 + 2] = a2;
  part[g][cq * 4 + 3] = a3;
  __syncthreads();

  float s = 0.f;
#pragma unroll
  for (int gg = 0; gg < 4; ++gg) s += part[gg][t];
  ws[(size_t)bid * CC + t] = s;             // regular store: re-read by B
}

// ---------------------------------------------------------------------------
// Kernel B: reduce 8 partials -> mean row in LDS; broadcast-write 32 rows.
// grid = BB*NBLK*NSUB = 512, block = 384.
// Store loop: i%CH4 is invariant (NT = 4*CH4), so each thread holds its mean
// float4 in a register and issues 8 pure nontemporal dwordx4 stores.
// ---------------------------------------------------------------------------
__global__ __launch_bounds__(NT) void bcast_f32(
    const float* __restrict__ ws, float* __restrict__ out) {
  __shared__ __align__(16) float smean[CC];

  int bid = blockIdx.x;                     // (b*NBLK + blk)*NSUB + sub
  int sub = bid & (NSUB - 1);
  int blk = (bid >> 4) & (NBLK - 1);
  int b   = bid >> 7;
  int t   = threadIdx.x;

  const float* wp = ws + (size_t)((b * NBLK + blk) * RCH) * CC + t;
  float s = 0.0f;
#pragma unroll
  for (int k = 0; k < RCH; ++k) s += wp[(size_t)k * CC];
  smean[t] = s * (1.0f / (float)BLK);
  __syncthreads();

  const f32x4* sv = (const f32x4*)smean;
  f32x4 val = sv[t % CH4];                  // loop-invariant mean chunk
  f32x4* ov = (f32x4*)(out + (size_t)(b * SS + blk * BLK + sub * RWS) * CC);
#pragma unroll
  for (int k = 0; k < (RWS * CH4) / NT; ++k)  // 8 iters
    __builtin_nontemporal_store(val, &ov[(size_t)k * NT + t]);
}

extern "C" void kernel_launch(void* const* d_in, const int* in_sizes, int n_in,
                              void* d_out, int out_size, void* d_ws,
                              size_t ws_size, hipStream_t stream) {
  const float* x = (const float*)d_in[0];
  float* out = (float*)d_out;
  float* ws = (float*)d_ws;  // 256*384*4 = 393 KB used (ws_size = 256 MiB)

  colsum_f32<<<BB * NBLK * RCH, NT, 0, stream>>>(x, ws);
  bcast_f32<<<BB * NBLK * NSUB, NT, 0, stream>>>(ws, out);
}